// Round 12
// baseline (105.922 us; speedup 1.0000x reference)
//
#include <hip/hip_runtime.h>
#include <cfloat>

// Problem constants: B=4, N=M=8192, D=3, fp32. Points ~ N(0,1)^3.
#define NPTS   32768           // points per tensor
#define NB     512             // x-buckets per grid
#define NGRIDS 8               // (tensor 0/1) x (batch 0..3)
#define XMINF  (-5.0f)
#define HB     0.01953125f     // 10/512, exact in fp32
#define INVHB  51.2f
#define WXF    0.40f           // half-window in x
#define GQ     512             // queries per group (64 lanes x QT)
#define QT     8               // queries per thread
#define SEG    64              // window slices per group (16 blocks x 4 waves)
#define NGRP   128             // total groups (65536/512)
#define BPG    16              // blocks per group

__device__ __forceinline__ unsigned fmap(float f){ unsigned u=__float_as_uint(f); return (u&0x80000000u)?~u:(u|0x80000000u); }
__device__ __forceinline__ float funmap(unsigned u){ u=(u&0x80000000u)?(u&0x7FFFFFFFu):~u; return __uint_as_float(u); }
__device__ __forceinline__ int bucketi(float x){
    int i = (int)floorf((x - XMINF) * INVHB);
    return min(max(i, 0), NB - 1);
}

// --- pass 1: per-grid histogram + scan + scatter + all init (ONE kernel) ---
// One block per (tensor,batch) grid: 1024 threads x 8 points each.
__global__ void __launch_bounds__(1024) k_prep(
        const float* __restrict__ gts, const float* __restrict__ preds,
        unsigned* __restrict__ offs, float4* __restrict__ sorted,
        unsigned* __restrict__ mins, unsigned* __restrict__ tickets,
        float* __restrict__ out, int out_size){
    __shared__ unsigned hist[NB];   // counts -> cursor
    __shared__ unsigned scn[NB];
    int g = blockIdx.x, t = threadIdx.x;
    int tensor = g >> 2, b = g & 3;
    const float* base = (tensor ? preds : gts) + (size_t)b * 8192 * 3;

    if (t < NB) hist[t] = 0u;
    __syncthreads();

    float px[8], py[8], pz[8]; int pb[8];
    #pragma unroll
    for (int i = 0; i < 8; ++i){
        int k = i * 1024 + t;
        px[i] = base[3*k]; py[i] = base[3*k+1]; pz[i] = base[3*k+2];
        pb[i] = bucketi(px[i]);
        atomicAdd(&hist[pb[i]], 1u);
    }
    __syncthreads();

    if (t < NB) scn[t] = hist[t];
    __syncthreads();
    for (int d = 1; d < NB; d <<= 1){
        unsigned v = 0u;
        if (t < NB && t >= d) v = scn[t - d];
        __syncthreads();
        if (t < NB) scn[t] += v;
        __syncthreads();
    }
    if (t < NB){
        offs[g*NB + t] = scn[t];            // bucket END (inclusive scan)
        hist[t] = scn[t] - hist[t];         // bucket START -> scatter cursor
    }
    __syncthreads();

    float4* dst = sorted + (size_t)g * 8192;
    #pragma unroll
    for (int i = 0; i < 8; ++i){
        unsigned slot = atomicAdd(&hist[pb[i]], 1u);
        dst[slot] = make_float4(px[i], py[i], pz[i],
                                0.5f*(px[i]*px[i] + py[i]*py[i] + pz[i]*pz[i]));
    }
    #pragma unroll
    for (int i = 0; i < 8; ++i) mins[g*8192 + i*1024 + t] = 0xFFFFFFFFu;
    if (g == 0){
        if (t < NGRP) tickets[t] = 0u;
        if (t < out_size) out[t] = 0.f;
    }
}

// --- pass 2: windowed brute + certificate + inline fallback + reduce -------
// 2048 blocks x 256 (8 blocks/CU resident): group g2 = bid>>4, slice w =
// (bid&15)*4 + wave (SEG=64 contiguous window slices). Round-11 lesson:
// 512 blocks = 8 waves/CU left VALUBusy at 33% (latency-unhidden) — the
// work needs only ~11 us of VALU; occupancy is the lever, not the loop.
// Merge = atomicMin; ticket winner (done==15; vmcnt+barrier ordering, NO
// threadfence — round-3 lesson) certifies (best <= margin-to-unscanned-
// bucket => exact), sums certified, rescans flagged with all 4 waves over
// the one-shot exact range |dx| <= best_passA.
__global__ void __launch_bounds__(256, 8) k_main(
        const unsigned* __restrict__ offs, const float4* __restrict__ sorted,
        unsigned* __restrict__ mins, unsigned* __restrict__ tickets,
        float* __restrict__ out){
    __shared__ float4 st[4][64];
    __shared__ unsigned done, fcnt;
    __shared__ unsigned fqid[GQ];
    __shared__ float    fb2v[GQ];

    int bid = blockIdx.x;                 // 2048
    int g2  = bid >> 4;                   // group 0..127
    int wv  = threadIdx.x >> 6, lane = threadIdx.x & 63;
    int w   = (bid & 15) * 4 + wv;        // slice 0..63
    int qg  = g2 >> 4;                    // query grid 0..7
    int tg  = ((qg >> 2) ^ 1) * 4 + (qg & 3);

    const float4* __restrict__ QS = sorted + (size_t)qg * 8192;
    const float4* __restrict__ TS = sorted + (size_t)tg * 8192;
    const unsigned* __restrict__ tof = offs + tg * NB;
    int q0 = (g2 & 15) * GQ + lane;       // same 512 queries for all waves

    float qx[QT], qy[QT], qz[QT], m[QT];
    float xlo = FLT_MAX, xhi = -FLT_MAX;
    #pragma unroll
    for (int k = 0; k < QT; ++k){
        float4 q = QS[q0 + 64*k];
        qx[k] = q.x; qy[k] = q.y; qz[k] = q.z; m[k] = FLT_MAX;
        xlo = fminf(xlo, q.x); xhi = fmaxf(xhi, q.x);
    }
    #pragma unroll
    for (int s = 1; s < 64; s <<= 1){
        xlo = fminf(xlo, __shfl_xor(xlo, s, 64));
        xhi = fmaxf(xhi, __shfl_xor(xhi, s, 64));
    }
    int blo = bucketi(xlo - WXF), bhi = bucketi(xhi + WXF);
    unsigned S = blo ? tof[blo - 1] : 0u;   // offs are inclusive ENDS
    unsigned E = tof[bhi];
    unsigned len = E - S;
    unsigned s0 = S + (len * (unsigned)w) / SEG;
    unsigned e0 = S + (len * (unsigned)(w + 1)) / SEG;

    // software-pipelined: load next chunk while computing current
    float4 cur = make_float4(0.f, 0.f, 0.f, 0.f);
    if (s0 + lane < e0) cur = TS[s0 + lane];
    for (unsigned bs = s0; bs < e0; bs += 64){
        st[wv][lane] = cur;
        unsigned ni = bs + 64 + lane;
        if (ni < e0) cur = TS[ni];
        int cnt = (int)min(64u, e0 - bs);
        for (int j = 0; j < cnt; ++j){
            float4 t = st[wv][j];            // broadcast ds_read_b128
            #pragma unroll
            for (int k = 0; k < QT; ++k){
                float s = fmaf(-qx[k], t.x, fmaf(-qy[k], t.y, fmaf(-qz[k], t.z, t.w)));
                m[k] = fminf(m[k], s);
            }
        }
    }

    #pragma unroll
    for (int k = 0; k < QT; ++k)
        atomicMin(&mins[qg*8192 + q0 + 64*k], fmap(m[k]));

    asm volatile("s_waitcnt vmcnt(0)" ::: "memory");  // my atomics complete
    __syncthreads();                                  // ... for ALL waves
    if (threadIdx.x == 0){ done = atomicAdd(&tickets[g2], 1u); fcnt = 0u; }
    __syncthreads();
    if (done != BPG - 1) return;

    // winner block: wave 0 certifies + sums certified; flagged -> LDS list
    if (wv == 0){
        float val = 0.f;
        #pragma unroll
        for (int k = 0; k < QT; ++k){
            unsigned gi = (unsigned)(qg*8192 + q0 + 64*k);
            unsigned u = atomicMin(&mins[gi], 0xFFFFFFFFu);  // coherent read
            float4 q = QS[q0 + 64*k];
            float b2 = 2.f*(funmap(u) + q.w);                // best dist^2
            float ml = (blo > 0)      ? (q.x - (XMINF + blo*HB))       : FLT_MAX;
            float mr = (bhi < NB - 1) ? ((XMINF + (bhi + 1)*HB) - q.x) : FLT_MAX;
            float mg = fminf(ml, mr) - 1e-5f;                // fp binning slack
            if ((mg > 0.f) && (b2 <= mg*mg)) val += b2;
            else { unsigned p = atomicAdd(&fcnt, 1u); fqid[p] = gi; fb2v[p] = b2; }
        }
        #pragma unroll
        for (int off = 32; off; off >>= 1) val += __shfl_down(val, off, 64);
        if (lane == 0) atomicAdd(out, val);
    }
    __syncthreads();                       // list + fcnt visible to all waves

    // all 4 waves process flagged queries round-robin; exact one-shot range
    unsigned n = fcnt;
    for (unsigned i = (unsigned)wv; i < n; i += 4u){
        unsigned qid = fqid[i];
        float b2p = fb2v[i];
        float4 q = sorted[qid];            // qid is a global sorted index
        int b1, b2i;
        if (b2p < 3.0e38f){                // finite pass-A best
            float best = sqrtf(fmaxf(b2p, 0.f));
            b1 = bucketi(q.x - best); b2i = bucketi(q.x + best);
        } else { b1 = 0; b2i = NB - 1; }   // empty window: full scan
        unsigned S2 = b1 ? tof[b1 - 1] : 0u;
        unsigned E2 = tof[b2i];
        float mm = FLT_MAX;
        unsigned j = S2 + (unsigned)lane;
        for (; j + 64u < E2; j += 128u){
            float4 a = TS[j], c = TS[j + 64u];
            mm = fminf(mm, fmaf(-q.x, a.x, fmaf(-q.y, a.y, fmaf(-q.z, a.z, a.w))));
            mm = fminf(mm, fmaf(-q.x, c.x, fmaf(-q.y, c.y, fmaf(-q.z, c.z, c.w))));
        }
        if (j < E2){
            float4 a = TS[j];
            mm = fminf(mm, fmaf(-q.x, a.x, fmaf(-q.y, a.y, fmaf(-q.z, a.z, a.w))));
        }
        #pragma unroll
        for (int s = 32; s; s >>= 1) mm = fminf(mm, __shfl_xor(mm, s, 64));
        if (lane == 0) atomicAdd(out, 2.f*(mm + q.w));
    }
}

extern "C" void kernel_launch(void* const* d_in, const int* in_sizes, int n_in,
                              void* d_out, int out_size, void* d_ws, size_t ws_size,
                              hipStream_t stream) {
    const float* gts   = (const float*)d_in[0];
    const float* preds = (const float*)d_in[1];
    float* out = (float*)d_out;

    char* ws = (char*)d_ws;
    unsigned* offs    = (unsigned*)(ws);                        // 16 KB
    unsigned* tickets = (unsigned*)(ws + 16384);                // 512 B
    float4*   sorted  = (float4*)  (ws + 65536);                // 1 MB
    unsigned* mins    = (unsigned*)(ws + 65536 + (size_t)NGRIDS*8192*16); // 256 KB

    k_prep<<<NGRIDS, 1024, 0, stream>>>(gts, preds, offs, sorted, mins,
                                        tickets, out, out_size);
    k_main<<<NGRP * BPG, 256, 0, stream>>>(offs, sorted, mins, tickets, out);
}

// Round 13
// 101.010 us; speedup vs baseline: 1.0486x; 1.0486x over previous
//
#include <hip/hip_runtime.h>
#include <cfloat>

// Problem constants: B=4, N=M=8192, D=3, fp32. Points ~ N(0,1)^3.
#define NPTS   32768           // points per tensor
#define NB     512             // x-buckets per grid
#define NGRIDS 8               // (tensor 0/1) x (batch 0..3)
#define XMINF  (-5.0f)
#define HB     0.01953125f     // 10/512, exact in fp32
#define INVHB  51.2f
#define WXF    0.40f           // half-window in x
#define GQ     512             // queries per group (64 lanes x QT)
#define QT     8               // queries per thread
#define BPG    8               // blocks per group (round-12 lesson: 16 doubled
                               // overhead for zero gain; occupancy wasn't the stall)
#define SEG    (BPG*4)         // 32 window slices per group
#define NGRP   128             // total groups (65536/512)

__device__ __forceinline__ unsigned fmap(float f){ unsigned u=__float_as_uint(f); return (u&0x80000000u)?~u:(u|0x80000000u); }
__device__ __forceinline__ float funmap(unsigned u){ u=(u&0x80000000u)?(u&0x7FFFFFFFu):~u; return __uint_as_float(u); }
__device__ __forceinline__ int bucketi(float x){
    int i = (int)floorf((x - XMINF) * INVHB);
    return min(max(i, 0), NB - 1);
}
// Accumulating 3-input min tied to the accumulator register (r5-r7 verified).
__device__ __forceinline__ void min3_acc(float& m, float a, float b) {
    asm("v_min3_f32 %0, %0, %1, %2" : "+v"(m) : "v"(a), "v"(b));
}

// --- pass 1: per-grid histogram + scan + scatter + all init (ONE kernel) ---
__global__ void __launch_bounds__(1024) k_prep(
        const float* __restrict__ gts, const float* __restrict__ preds,
        unsigned* __restrict__ offs, float4* __restrict__ sorted,
        unsigned* __restrict__ mins, unsigned* __restrict__ tickets,
        float* __restrict__ out, int out_size){
    __shared__ unsigned hist[NB];   // counts -> cursor
    __shared__ unsigned scn[NB];
    int g = blockIdx.x, t = threadIdx.x;
    int tensor = g >> 2, b = g & 3;
    const float* base = (tensor ? preds : gts) + (size_t)b * 8192 * 3;

    if (t < NB) hist[t] = 0u;
    __syncthreads();

    float px[8], py[8], pz[8]; int pb[8];
    #pragma unroll
    for (int i = 0; i < 8; ++i){
        int k = i * 1024 + t;
        px[i] = base[3*k]; py[i] = base[3*k+1]; pz[i] = base[3*k+2];
        pb[i] = bucketi(px[i]);
        atomicAdd(&hist[pb[i]], 1u);
    }
    __syncthreads();

    if (t < NB) scn[t] = hist[t];
    __syncthreads();
    for (int d = 1; d < NB; d <<= 1){
        unsigned v = 0u;
        if (t < NB && t >= d) v = scn[t - d];
        __syncthreads();
        if (t < NB) scn[t] += v;
        __syncthreads();
    }
    if (t < NB){
        offs[g*NB + t] = scn[t];            // bucket END (inclusive scan)
        hist[t] = scn[t] - hist[t];         // bucket START -> scatter cursor
    }
    __syncthreads();

    float4* dst = sorted + (size_t)g * 8192;
    #pragma unroll
    for (int i = 0; i < 8; ++i){
        unsigned slot = atomicAdd(&hist[pb[i]], 1u);
        dst[slot] = make_float4(px[i], py[i], pz[i],
                                0.5f*(px[i]*px[i] + py[i]*py[i] + pz[i]*pz[i]));
    }
    #pragma unroll
    for (int i = 0; i < 8; ++i) mins[g*8192 + i*1024 + t] = 0xFFFFFFFFu;
    if (g == 0){
        if (t < NGRP) tickets[t] = 0u;
        if (t < out_size) out[t] = 0.f;
    }
}

// --- pass 2: windowed brute + certificate + inline fallback + reduce -------
// 1024 blocks x 256. Round-12 lesson: the 33% VALUBusy stall was the
// runtime-variable inner trip count (one ds_read + lgkmcnt(0) + 32 VALU per
// iteration exposes ~120cy LDS latency). Fix: CONSTANT 64-target chunks —
// staging index clamped to e0-1 (duplicate targets are harmless under min)
// so the j-loop fully unrolls and ds_reads pipeline (r7 measured 105%
// VALUBusy with this shape). Merge = atomicMin; ticket winner (vmcnt+barrier,
// NO threadfence — round-3 lesson) certifies via margin-to-unscanned-bucket,
// sums certified, rescans flagged with all 4 waves over |dx| <= best_passA.
__global__ void __launch_bounds__(256, 8) k_main(
        const unsigned* __restrict__ offs, const float4* __restrict__ sorted,
        unsigned* __restrict__ mins, unsigned* __restrict__ tickets,
        float* __restrict__ out){
    __shared__ float4 st[4][64];
    __shared__ unsigned done, fcnt;
    __shared__ unsigned fqid[GQ];
    __shared__ float    fb2v[GQ];

    int bid = blockIdx.x;                 // 1024
    int g2  = bid >> 3;                   // group 0..127
    int wv  = threadIdx.x >> 6, lane = threadIdx.x & 63;
    int w   = (bid & 7) * 4 + wv;         // slice 0..31
    int qg  = g2 >> 4;                    // query grid 0..7
    int tg  = ((qg >> 2) ^ 1) * 4 + (qg & 3);

    const float4* __restrict__ QS = sorted + (size_t)qg * 8192;
    const float4* __restrict__ TS = sorted + (size_t)tg * 8192;
    const unsigned* __restrict__ tof = offs + tg * NB;
    int q0 = (g2 & 15) * GQ + lane;       // same 512 queries for all waves

    float qx[QT], qy[QT], qz[QT], m[QT];
    float xlo = FLT_MAX, xhi = -FLT_MAX;
    #pragma unroll
    for (int k = 0; k < QT; ++k){
        float4 q = QS[q0 + 64*k];
        qx[k] = q.x; qy[k] = q.y; qz[k] = q.z; m[k] = FLT_MAX;
        xlo = fminf(xlo, q.x); xhi = fmaxf(xhi, q.x);
    }
    #pragma unroll
    for (int s = 1; s < 64; s <<= 1){
        xlo = fminf(xlo, __shfl_xor(xlo, s, 64));
        xhi = fmaxf(xhi, __shfl_xor(xhi, s, 64));
    }
    int blo = bucketi(xlo - WXF), bhi = bucketi(xhi + WXF);
    unsigned S = blo ? tof[blo - 1] : 0u;   // offs are inclusive ENDS
    unsigned E = tof[bhi];
    unsigned len = E - S;
    unsigned s0 = S + (len * (unsigned)w) / SEG;
    unsigned e0 = S + (len * (unsigned)(w + 1)) / SEG;

    if (s0 < e0){
        // software-pipelined staging, CLAMPED index -> constant 64-trip chunks
        float4 cur = TS[min(s0 + (unsigned)lane, e0 - 1u)];
        for (unsigned bs = s0; bs < e0; bs += 64){
            st[wv][lane] = cur;
            cur = TS[min(bs + 64u + (unsigned)lane, e0 - 1u)]; // dup on last: harmless
            #pragma unroll 4
            for (int j = 0; j < 64; j += 2){
                float4 t0 = st[wv][j], t1 = st[wv][j+1];
                #pragma unroll
                for (int k = 0; k < QT; ++k){
                    float s0v = fmaf(-qx[k], t0.x,
                                fmaf(-qy[k], t0.y,
                                fmaf(-qz[k], t0.z, t0.w)));
                    float s1v = fmaf(-qx[k], t1.x,
                                fmaf(-qy[k], t1.y,
                                fmaf(-qz[k], t1.z, t1.w)));
                    min3_acc(m[k], s0v, s1v);
                }
            }
        }
    }

    #pragma unroll
    for (int k = 0; k < QT; ++k)
        atomicMin(&mins[qg*8192 + q0 + 64*k], fmap(m[k]));

    asm volatile("s_waitcnt vmcnt(0)" ::: "memory");  // my atomics complete
    __syncthreads();                                  // ... for ALL waves
    if (threadIdx.x == 0){ done = atomicAdd(&tickets[g2], 1u); fcnt = 0u; }
    __syncthreads();
    if (done != BPG - 1) return;

    // winner block: wave 0 certifies + sums certified; flagged -> LDS list
    if (wv == 0){
        float val = 0.f;
        #pragma unroll
        for (int k = 0; k < QT; ++k){
            unsigned gi = (unsigned)(qg*8192 + q0 + 64*k);
            unsigned u = atomicMin(&mins[gi], 0xFFFFFFFFu);  // coherent read
            float4 q = QS[q0 + 64*k];
            float b2 = 2.f*(funmap(u) + q.w);                // best dist^2
            float ml = (blo > 0)      ? (q.x - (XMINF + blo*HB))       : FLT_MAX;
            float mr = (bhi < NB - 1) ? ((XMINF + (bhi + 1)*HB) - q.x) : FLT_MAX;
            float mg = fminf(ml, mr) - 1e-5f;                // fp binning slack
            if ((mg > 0.f) && (b2 <= mg*mg)) val += b2;
            else { unsigned p = atomicAdd(&fcnt, 1u); fqid[p] = gi; fb2v[p] = b2; }
        }
        #pragma unroll
        for (int off = 32; off; off >>= 1) val += __shfl_down(val, off, 64);
        if (lane == 0) atomicAdd(out, val);
    }
    __syncthreads();                       // list + fcnt visible to all waves

    // all 4 waves process flagged queries round-robin; exact one-shot range
    unsigned n = fcnt;
    for (unsigned i = (unsigned)wv; i < n; i += 4u){
        unsigned qid = fqid[i];
        float b2p = fb2v[i];
        float4 q = sorted[qid];            // qid is a global sorted index
        int b1, b2i;
        if (b2p < 3.0e38f){                // finite pass-A best
            float best = sqrtf(fmaxf(b2p, 0.f));
            b1 = bucketi(q.x - best); b2i = bucketi(q.x + best);
        } else { b1 = 0; b2i = NB - 1; }   // empty window: full scan
        unsigned S2 = b1 ? tof[b1 - 1] : 0u;
        unsigned E2 = tof[b2i];
        float mm = FLT_MAX;
        unsigned j = S2 + (unsigned)lane;
        for (; j + 64u < E2; j += 128u){
            float4 a = TS[j], c = TS[j + 64u];
            mm = fminf(mm, fmaf(-q.x, a.x, fmaf(-q.y, a.y, fmaf(-q.z, a.z, a.w))));
            mm = fminf(mm, fmaf(-q.x, c.x, fmaf(-q.y, c.y, fmaf(-q.z, c.z, c.w))));
        }
        if (j < E2){
            float4 a = TS[j];
            mm = fminf(mm, fmaf(-q.x, a.x, fmaf(-q.y, a.y, fmaf(-q.z, a.z, a.w))));
        }
        #pragma unroll
        for (int s = 32; s; s >>= 1) mm = fminf(mm, __shfl_xor(mm, s, 64));
        if (lane == 0) atomicAdd(out, 2.f*(mm + q.w));
    }
}

extern "C" void kernel_launch(void* const* d_in, const int* in_sizes, int n_in,
                              void* d_out, int out_size, void* d_ws, size_t ws_size,
                              hipStream_t stream) {
    const float* gts   = (const float*)d_in[0];
    const float* preds = (const float*)d_in[1];
    float* out = (float*)d_out;

    char* ws = (char*)d_ws;
    unsigned* offs    = (unsigned*)(ws);                        // 16 KB
    unsigned* tickets = (unsigned*)(ws + 16384);                // 512 B
    float4*   sorted  = (float4*)  (ws + 65536);                // 1 MB
    unsigned* mins    = (unsigned*)(ws + 65536 + (size_t)NGRIDS*8192*16); // 256 KB

    k_prep<<<NGRIDS, 1024, 0, stream>>>(gts, preds, offs, sorted, mins,
                                        tickets, out, out_size);
    k_main<<<NGRP * BPG, 256, 0, stream>>>(offs, sorted, mins, tickets, out);
}